// Round 7
// baseline (181.298 us; speedup 1.0000x reference)
//
#include <hip/hip_runtime.h>

// Problem constants (from reference): B=4, S=2048, V=64, D=1024, P=8, H=42, K=49152
#define BB 4
#define SS 2048
#define VV 64
#define DD 1024
#define PP 8
#define HH 42
#define KK 49152
#define NCHUNK 64   // s-chunks per batch (32 rows each) — R0 granularity

static constexpr float F_EPS = 1e-12f;
// n[b,s,p] = c/max(sqrt(S)*c,eps) = 1/sqrt(S) if c>0 else 0, so the softmax
// weight (Z cancels in cos) is exp(n) = ALPHA if dot>0 else 1.
static constexpr float ALPHA = 1.02234304f;

// ---------------------------------------------------------------------------
// kU (512 threads): grid (64, 4) — PURE U-pass, byte-identical to R6 (proven).
// NO device fences anywhere: R5 proved __threadfence => full-L2 writeback on
// gfx950 (WRITE_SIZE 2->8.3MB, kU 41->79us). Launch boundary is cheaper.
// ---------------------------------------------------------------------------
__global__ __launch_bounds__(512) void kU(
    const float* __restrict__ ctx, const float* __restrict__ lora,
    float* __restrict__ part) {
  __shared__ float smem[PP * DD + 16 + 32 * PP];  // 33 KB
  const int t = threadIdx.x;
  const int b = blockIdx.y;
  const int chunk = blockIdx.x;
  float* u_lds = smem;
  float* w_lds = smem + PP * DD + 16;
  {
    const float4* lora4 = (const float4*)lora;
    float4* u4w = (float4*)u_lds;
    #pragma unroll
    for (int i = t; i < PP * DD / 4; i += 512) {
      float4 e = lora4[i];
      float4 u;
      u.x = e.x / fmaxf(2.0f * fabsf(e.x), F_EPS);
      u.y = e.y / fmaxf(2.0f * fabsf(e.y), F_EPS);
      u.z = e.z / fmaxf(2.0f * fabsf(e.z), F_EPS);
      u.w = e.w / fmaxf(2.0f * fabsf(e.w), F_EPS);
      u4w[i] = u;
    }
  }
  __syncthreads();
  const int wave = t >> 6, lane = t & 63;
  const int rbase = b * SS + chunk * 32 + wave * 4;
  const float4* ctx4 = (const float4*)ctx;
  const float4* u4 = (const float4*)u_lds;
  float dot[4][PP];
  #pragma unroll
  for (int i = 0; i < 4; ++i)
    #pragma unroll
    for (int p = 0; p < PP; ++p) dot[i][p] = 0.f;
  #pragma unroll
  for (int j = 0; j < 4; ++j) {
    float4 c[4];
    #pragma unroll
    for (int i = 0; i < 4; ++i)
      c[i] = ctx4[(size_t)(rbase + i) * 256 + j * 64 + lane];
    #pragma unroll
    for (int p = 0; p < PP; ++p) {
      float4 u = u4[p * 256 + j * 64 + lane];
      #pragma unroll
      for (int i = 0; i < 4; ++i)
        dot[i][p] += c[i].x * u.x + c[i].y * u.y + c[i].z * u.z + c[i].w * u.w;
    }
  }
  const int sel = lane & 7;
  #pragma unroll
  for (int i = 0; i < 4; ++i) {
    float d0 = dot[i][0], d1 = dot[i][1], d2 = dot[i][2], d3 = dot[i][3];
    float d4 = dot[i][4], d5 = dot[i][5], d6 = dot[i][6], d7 = dot[i][7];
    #pragma unroll
    for (int m = 1; m <= 4; m <<= 1) {
      d0 += __shfl_xor(d0, m, 64); d1 += __shfl_xor(d1, m, 64);
      d2 += __shfl_xor(d2, m, 64); d3 += __shfl_xor(d3, m, 64);
      d4 += __shfl_xor(d4, m, 64); d5 += __shfl_xor(d5, m, 64);
      d6 += __shfl_xor(d6, m, 64); d7 += __shfl_xor(d7, m, 64);
    }
    float v = d0;
    v = (sel == 1) ? d1 : v; v = (sel == 2) ? d2 : v;
    v = (sel == 3) ? d3 : v; v = (sel == 4) ? d4 : v;
    v = (sel == 5) ? d5 : v; v = (sel == 6) ? d6 : v;
    v = (sel == 7) ? d7 : v;
    v += __shfl_xor(v, 8, 64);
    v += __shfl_xor(v, 16, 64);
    v += __shfl_xor(v, 32, 64);
    if (lane < PP)
      w_lds[(wave * 4 + i) * PP + lane] = (v > 0.0f) ? ALPHA : 1.0f;
  }
  __syncthreads();
  // phase 3: weighted accumulation, thread owns d-cols {2t, 2t+1}
  float2 acc[PP];
  #pragma unroll
  for (int p = 0; p < PP; ++p) acc[p] = make_float2(0.f, 0.f);
  const float2* ctx2 = (const float2*)ctx;
  const float4* w4 = (const float4*)w_lds;
  #pragma unroll 4
  for (int sl = 0; sl < 32; ++sl) {
    float2 c = ctx2[(size_t)(b * SS + chunk * 32 + sl) * 512 + t];
    float4 wa = w4[sl * 2];
    float4 wb = w4[sl * 2 + 1];
    float w[PP] = {wa.x, wa.y, wa.z, wa.w, wb.x, wb.y, wb.z, wb.w};
    #pragma unroll
    for (int p = 0; p < PP; ++p) {
      acc[p].x += w[p] * c.x;
      acc[p].y += w[p] * c.y;
    }
  }
  float2* part2 = (float2*)part;
  #pragma unroll
  for (int p = 0; p < PP; ++p)
    part2[(size_t)((b * NCHUNK + chunk) * PP + p) * 512 + t] = acc[p];
}

// ---------------------------------------------------------------------------
// k4h (512 threads): grid (32 + 64).
// Blocks x<32: cos reduction (byte-identical logic to R6).
// Blocks x>=32: h_all rows 8-at-a-time (g = x-32, rows g*8..g*8+8):
//   stage 8 rows (32 KB) as one contiguous float4 copy; thread (q=t>>6,
//   h=t&63) walks its 128-d octant: one scalar w1 load feeds 8 FMAs
//   (w1 L2 traffic 88 MB -> 11 MB vs R6's 1-row blocks); broadcast LDS
//   reads (conflict-free); cross-octant reduce via 16 KB partial.
// ---------------------------------------------------------------------------
__global__ __launch_bounds__(512) void k4h(
    const float* __restrict__ part, const float* __restrict__ lora,
    const float* __restrict__ tables, const float* __restrict__ w1,
    const float* __restrict__ b1, float* __restrict__ cos_ws,
    float* __restrict__ h_all) {
  __shared__ float smem[8 * DD + 8 * 8 * 64];  // 48 KB (reduce path uses 24 f)
  const int t = threadIdx.x;
  if (blockIdx.x < 32) {
    const int p = blockIdx.x & 7, b = blockIdx.x >> 3;
    const float2* p2 = (const float2*)part;
    float avx = 0.f, avy = 0.f;
    #pragma unroll 8
    for (int c = 0; c < NCHUNK; ++c) {
      float2 x = p2[(size_t)((b * NCHUNK + c) * PP + p) * 512 + t];
      avx += x.x; avy += x.y;
    }
    float2 e = ((const float2*)lora)[p * 512 + t];
    float dt = avx * e.x + avy * e.y;
    float a2 = avx * avx + avy * avy;
    float e2 = e.x * e.x + e.y * e.y;
    #pragma unroll
    for (int m = 32; m >= 1; m >>= 1) {
      dt += __shfl_xor(dt, m, 64);
      a2 += __shfl_xor(a2, m, 64);
      e2 += __shfl_xor(e2, m, 64);
    }
    const int wave = t >> 6, lane = t & 63;
    if (lane == 0) {
      smem[wave * 3 + 0] = dt;
      smem[wave * 3 + 1] = a2;
      smem[wave * 3 + 2] = e2;
    }
    __syncthreads();
    if (t == 0) {
      float Dv = 0.f, Av = 0.f, Ev = 0.f;
      #pragma unroll
      for (int w8 = 0; w8 < 8; ++w8) {
        Dv += smem[w8 * 3 + 0];
        Av += smem[w8 * 3 + 1];
        Ev += smem[w8 * 3 + 2];
      }
      cos_ws[b * PP + p] = Dv / fmaxf(sqrtf(Ev) * sqrtf(Av), 1e-8f);
    }
  } else {
    // ---------------- h_all, 8 rows per block ----------------
    float* row_lds = smem;               // 8*DD floats (32 KB)
    float* partial = smem + 8 * DD;      // [q][r][64] (16 KB)
    const int rbase = (blockIdx.x - 32) * 8;
    {
      const float4* src = (const float4*)(tables + (size_t)rbase * DD);
      float4* dst = (float4*)row_lds;
      #pragma unroll
      for (int i = t; i < 8 * DD / 4; i += 512) dst[i] = src[i];
    }
    __syncthreads();
    const int h = t & 63, q = t >> 6;  // q in 0..7, 128-d octant
    float acc[8];
    #pragma unroll
    for (int r = 0; r < 8; ++r) acc[r] = 0.f;
    if (h < HH) {
      const int d0 = q * 128;
      #pragma unroll 8
      for (int dl = 0; dl < 128; ++dl) {
        float wv = w1[(size_t)(d0 + dl) * HH + h];
        #pragma unroll
        for (int r = 0; r < 8; ++r)
          acc[r] += row_lds[r * DD + d0 + dl] * wv;
      }
    }
    #pragma unroll
    for (int r = 0; r < 8; ++r) partial[(q * 8 + r) * 64 + h] = acc[r];
    __syncthreads();
    // t covers (r = t>>6, h = t&63)
    const int r = t >> 6;
    if (h < HH) {
      float s = 0.0f;
      #pragma unroll
      for (int q8 = 0; q8 < 8; ++q8) s += partial[(q8 * 8 + r) * 64 + h];
      h_all[(size_t)(rbase + r) * HH + h] = tanhf(s + b1[h]);
    }
  }
}

// ---------------------------------------------------------------------------
// K7: out[bv,k] = hg[bv,:] @ w2[:,k] + b2[k], hg = sum_p gate[b,p]*h_all[gather]
// Block = (b, k-tile of 128). Changes vs R6: (1) gate computed redundantly
// per-thread in registers (8 broadcast loads + ~40 VALU) — kills the serial
// t==0 section AND the first barrier (stage+gather are now barrier-free);
// (2) w2 staged as float4 (5.25 iters/thread vs 21 scalar).
// ---------------------------------------------------------------------------
__global__ __launch_bounds__(256) void k7_out(
    const float* __restrict__ w2, const float* __restrict__ b2,
    const float* __restrict__ h_all, const float* __restrict__ cos_ws,
    const int* __restrict__ prefix, float* __restrict__ out) {
  __shared__ float hg_lds[HH * 64];    // [h][v]
  __shared__ float w2_lds[HH * 128];   // [h][kk]
  const int t = threadIdx.x;
  const int b = blockIdx.y;
  const size_t kbase = (size_t)blockIdx.x * 128;
  // stage w2 tile, float4 (1344 float4 over 256 threads)
  {
    const float4* w2g = (const float4*)w2;
    float4* w2l = (float4*)w2_lds;
    for (int i = t; i < HH * 32; i += 256) {
      int h = i >> 5, k4 = i & 31;
      w2l[i] = w2g[(size_t)h * (KK / 4) + (kbase >> 2) + k4];
    }
  }
  // per-thread redundant gate (no serial section, no barrier needed)
  float gate[PP];
  {
    float c[PP];
    float m = -1e30f;
    #pragma unroll
    for (int p = 0; p < PP; ++p) { c[p] = cos_ws[b * PP + p]; m = fmaxf(m, c[p]); }
    float s = 0.0f;
    #pragma unroll
    for (int p = 0; p < PP; ++p) { c[p] = expf(c[p] - m); s += c[p]; }
    float inv = 1.0f / s;
    float m2 = -1e30f;
    #pragma unroll
    for (int p = 0; p < PP; ++p) { c[p] *= inv; m2 = fmaxf(m2, c[p]); }
    float s2 = 0.0f;
    #pragma unroll
    for (int p = 0; p < PP; ++p) { c[p] = expf(c[p] - m2); s2 += c[p]; }
    float inv2 = 1.0f / s2;
    #pragma unroll
    for (int p = 0; p < PP; ++p) gate[p] = c[p] * inv2;
  }
  for (int idx = t; idx < 64 * HH; idx += 256) {
    int v = idx / HH;
    int h = idx - v * HH;
    int tokv = prefix[b * VV + v];
    float s = 0.0f;
    #pragma unroll
    for (int p = 0; p < PP; ++p)
      s += gate[p] * h_all[(size_t)(p * VV + tokv) * HH + h];
    hg_lds[h * 64 + v] = s;
  }
  __syncthreads();
  const int tk = t & 31, tb = t >> 5;
  float4 acc[8];
  #pragma unroll
  for (int i = 0; i < 8; ++i) acc[i] = make_float4(0.f, 0.f, 0.f, 0.f);
  const float4* w24 = (const float4*)w2_lds;
  const float4* hg4 = (const float4*)hg_lds;
  #pragma unroll 2
  for (int h = 0; h < HH; ++h) {
    float4 wv = w24[h * 32 + tk];
    float4 g0 = hg4[h * 16 + tb * 2];
    float4 g1 = hg4[h * 16 + tb * 2 + 1];
    float gg[8] = {g0.x, g0.y, g0.z, g0.w, g1.x, g1.y, g1.z, g1.w};
    #pragma unroll
    for (int i = 0; i < 8; ++i) {
      acc[i].x += gg[i] * wv.x;
      acc[i].y += gg[i] * wv.y;
      acc[i].z += gg[i] * wv.z;
      acc[i].w += gg[i] * wv.w;
    }
  }
  float4 b2v = ((const float4*)b2)[(kbase >> 2) + tk];
  float4* out4 = (float4*)out;
  #pragma unroll
  for (int i = 0; i < 8; ++i) {
    int bv = b * 64 + tb * 8 + i;
    float4 o;
    o.x = acc[i].x + b2v.x;
    o.y = acc[i].y + b2v.y;
    o.z = acc[i].z + b2v.z;
    o.w = acc[i].w + b2v.w;
    out4[(((size_t)bv * KK + kbase) >> 2) + tk] = o;
  }
}

extern "C" void kernel_launch(void* const* d_in, const int* in_sizes, int n_in,
                              void* d_out, int out_size, void* d_ws, size_t ws_size,
                              hipStream_t stream) {
  const int* prefix = (const int*)d_in[0];
  const float* ctx = (const float*)d_in[1];
  const float* tables = (const float*)d_in[2];
  const float* lora = (const float*)d_in[3];
  const float* w1 = (const float*)d_in[4];
  const float* b1 = (const float*)d_in[5];
  const float* w2 = (const float*)d_in[6];
  const float* b2 = (const float*)d_in[7];
  float* out = (float*)d_out;
  char* ws = (char*)d_ws;
  // workspace (bytes): part 8388608 | cos 128 | h_all 86016  (~8.5 MB)
  float* part = (float*)ws;
  float* cos_ws = (float*)(ws + 8388608);
  float* h_all = (float*)(ws + 8388608 + 128);

  kU<<<dim3(64, 4), 512, 0, stream>>>(ctx, lora, part);
  k4h<<<dim3(32 + 64), 512, 0, stream>>>(part, lora, tables, w1, b1,
                                         cos_ws, h_all);
  k7_out<<<dim3(384, 4), 256, 0, stream>>>(w2, b2, h_all, cos_ws, prefix, out);
}

// Round 8
// 148.069 us; speedup vs baseline: 1.2244x; 1.2244x over previous
//
#include <hip/hip_runtime.h>

// Problem constants (from reference): B=4, S=2048, V=64, D=1024, P=8, H=42, K=49152
#define BB 4
#define SS 2048
#define VV 64
#define DD 1024
#define PP 8
#define HH 42
#define KK 49152
#define NCHUNK 64   // s-chunks per batch (32 rows each) — R0 granularity

static constexpr float F_EPS = 1e-12f;
// n[b,s,p] = c/max(sqrt(S)*c,eps) = 1/sqrt(S) if c>0 else 0, so the softmax
// weight (Z cancels in cos) is exp(n) = ALPHA if dot>0 else 1.
static constexpr float ALPHA = 1.02234304f;

// ---------------------------------------------------------------------------
// kU (512 threads): grid (64, 4) — PURE U-pass, byte-identical to R6 (proven).
// NO device fences anywhere: R5 proved __threadfence => full-L2 writeback on
// gfx950 (WRITE_SIZE 2->8.3MB, kU 41->79us). Launch boundary is cheaper.
// ---------------------------------------------------------------------------
__global__ __launch_bounds__(512) void kU(
    const float* __restrict__ ctx, const float* __restrict__ lora,
    float* __restrict__ part) {
  __shared__ float smem[PP * DD + 16 + 32 * PP];  // 33 KB
  const int t = threadIdx.x;
  const int b = blockIdx.y;
  const int chunk = blockIdx.x;
  float* u_lds = smem;
  float* w_lds = smem + PP * DD + 16;
  {
    const float4* lora4 = (const float4*)lora;
    float4* u4w = (float4*)u_lds;
    #pragma unroll
    for (int i = t; i < PP * DD / 4; i += 512) {
      float4 e = lora4[i];
      float4 u;
      u.x = e.x / fmaxf(2.0f * fabsf(e.x), F_EPS);
      u.y = e.y / fmaxf(2.0f * fabsf(e.y), F_EPS);
      u.z = e.z / fmaxf(2.0f * fabsf(e.z), F_EPS);
      u.w = e.w / fmaxf(2.0f * fabsf(e.w), F_EPS);
      u4w[i] = u;
    }
  }
  __syncthreads();
  const int wave = t >> 6, lane = t & 63;
  const int rbase = b * SS + chunk * 32 + wave * 4;
  const float4* ctx4 = (const float4*)ctx;
  const float4* u4 = (const float4*)u_lds;
  float dot[4][PP];
  #pragma unroll
  for (int i = 0; i < 4; ++i)
    #pragma unroll
    for (int p = 0; p < PP; ++p) dot[i][p] = 0.f;
  #pragma unroll
  for (int j = 0; j < 4; ++j) {
    float4 c[4];
    #pragma unroll
    for (int i = 0; i < 4; ++i)
      c[i] = ctx4[(size_t)(rbase + i) * 256 + j * 64 + lane];
    #pragma unroll
    for (int p = 0; p < PP; ++p) {
      float4 u = u4[p * 256 + j * 64 + lane];
      #pragma unroll
      for (int i = 0; i < 4; ++i)
        dot[i][p] += c[i].x * u.x + c[i].y * u.y + c[i].z * u.z + c[i].w * u.w;
    }
  }
  const int sel = lane & 7;
  #pragma unroll
  for (int i = 0; i < 4; ++i) {
    float d0 = dot[i][0], d1 = dot[i][1], d2 = dot[i][2], d3 = dot[i][3];
    float d4 = dot[i][4], d5 = dot[i][5], d6 = dot[i][6], d7 = dot[i][7];
    #pragma unroll
    for (int m = 1; m <= 4; m <<= 1) {
      d0 += __shfl_xor(d0, m, 64); d1 += __shfl_xor(d1, m, 64);
      d2 += __shfl_xor(d2, m, 64); d3 += __shfl_xor(d3, m, 64);
      d4 += __shfl_xor(d4, m, 64); d5 += __shfl_xor(d5, m, 64);
      d6 += __shfl_xor(d6, m, 64); d7 += __shfl_xor(d7, m, 64);
    }
    float v = d0;
    v = (sel == 1) ? d1 : v; v = (sel == 2) ? d2 : v;
    v = (sel == 3) ? d3 : v; v = (sel == 4) ? d4 : v;
    v = (sel == 5) ? d5 : v; v = (sel == 6) ? d6 : v;
    v = (sel == 7) ? d7 : v;
    v += __shfl_xor(v, 8, 64);
    v += __shfl_xor(v, 16, 64);
    v += __shfl_xor(v, 32, 64);
    if (lane < PP)
      w_lds[(wave * 4 + i) * PP + lane] = (v > 0.0f) ? ALPHA : 1.0f;
  }
  __syncthreads();
  // phase 3: weighted accumulation, thread owns d-cols {2t, 2t+1}
  float2 acc[PP];
  #pragma unroll
  for (int p = 0; p < PP; ++p) acc[p] = make_float2(0.f, 0.f);
  const float2* ctx2 = (const float2*)ctx;
  const float4* w4 = (const float4*)w_lds;
  #pragma unroll 4
  for (int sl = 0; sl < 32; ++sl) {
    float2 c = ctx2[(size_t)(b * SS + chunk * 32 + sl) * 512 + t];
    float4 wa = w4[sl * 2];
    float4 wb = w4[sl * 2 + 1];
    float w[PP] = {wa.x, wa.y, wa.z, wa.w, wb.x, wb.y, wb.z, wb.w};
    #pragma unroll
    for (int p = 0; p < PP; ++p) {
      acc[p].x += w[p] * c.x;
      acc[p].y += w[p] * c.y;
    }
  }
  float2* part2 = (float2*)part;
  #pragma unroll
  for (int p = 0; p < PP; ++p)
    part2[(size_t)((b * NCHUNK + chunk) * PP + p) * 512 + t] = acc[p];
}

// ---------------------------------------------------------------------------
// k4h (512 threads): grid (32 + 512) — byte-identical to R6 (proven fast).
// R7's 8-row h-blocks shrank the grid to 96 blocks -> 48us latency disaster
// (occupancy 5%, HBM 1.6%). Law of this workload: keep grids >= ~500 blocks.
// Blocks x<32: cos reduction. Blocks x>=32: h_all row r = x-32.
// ---------------------------------------------------------------------------
__global__ __launch_bounds__(512) void k4h(
    const float* __restrict__ part, const float* __restrict__ lora,
    const float* __restrict__ tables, const float* __restrict__ w1,
    const float* __restrict__ b1, float* __restrict__ cos_ws,
    float* __restrict__ h_all) {
  __shared__ float smem[DD + 512];  // h: row(1024)+partial(512); k4: 24 floats
  const int t = threadIdx.x;
  if (blockIdx.x < 32) {
    const int p = blockIdx.x & 7, b = blockIdx.x >> 3;
    const float2* p2 = (const float2*)part;
    float avx = 0.f, avy = 0.f;
    #pragma unroll 8
    for (int c = 0; c < NCHUNK; ++c) {
      float2 x = p2[(size_t)((b * NCHUNK + c) * PP + p) * 512 + t];
      avx += x.x; avy += x.y;
    }
    float2 e = ((const float2*)lora)[p * 512 + t];
    float dt = avx * e.x + avy * e.y;
    float a2 = avx * avx + avy * avy;
    float e2 = e.x * e.x + e.y * e.y;
    #pragma unroll
    for (int m = 32; m >= 1; m >>= 1) {
      dt += __shfl_xor(dt, m, 64);
      a2 += __shfl_xor(a2, m, 64);
      e2 += __shfl_xor(e2, m, 64);
    }
    const int wave = t >> 6, lane = t & 63;
    if (lane == 0) {
      smem[wave * 3 + 0] = dt;
      smem[wave * 3 + 1] = a2;
      smem[wave * 3 + 2] = e2;
    }
    __syncthreads();
    if (t == 0) {
      float Dv = 0.f, Av = 0.f, Ev = 0.f;
      #pragma unroll
      for (int w8 = 0; w8 < 8; ++w8) {
        Dv += smem[w8 * 3 + 0];
        Av += smem[w8 * 3 + 1];
        Ev += smem[w8 * 3 + 2];
      }
      cos_ws[b * PP + p] = Dv / fmaxf(sqrtf(Ev) * sqrtf(Av), 1e-8f);
    }
  } else {
    // ---------------- h_all row (512 threads, 8 octants) ----------------
    float* row_lds = smem;            // DD floats
    float* partial = smem + DD;       // 512 floats
    const int r = blockIdx.x - 32;
    ((float2*)row_lds)[t] = ((const float2*)(tables + (size_t)r * DD))[t];
    __syncthreads();
    const int h = t & 63, q = t >> 6;  // q in 0..7, 128-d octant
    float acc = 0.0f;
    if (h < HH) {
      const int d0 = q * 128;
      #pragma unroll 8
      for (int dl = 0; dl < 128; ++dl) {
        acc += row_lds[d0 + dl] * w1[(size_t)(d0 + dl) * HH + h];
      }
    }
    partial[q * 64 + h] = acc;
    __syncthreads();
    if (t < HH) {
      float s = 0.0f;
      #pragma unroll
      for (int q8 = 0; q8 < 8; ++q8) s += partial[q8 * 64 + t];
      h_all[(size_t)r * HH + t] = tanhf(s + b1[t]);
    }
  }
}

// ---------------------------------------------------------------------------
// K7: out[bv,k] = hg[bv,:] @ w2[:,k] + b2[k], hg = sum_p gate[b,p]*h_all[gather]
// Block = (b, k-tile of 128). R7 version (kept — attribution said neutral-to-
// positive): (1) gate computed redundantly per-thread in registers (~40 VALU)
// — no serial t==0 section, no first barrier; (2) w2 staged as float4.
// ---------------------------------------------------------------------------
__global__ __launch_bounds__(256) void k7_out(
    const float* __restrict__ w2, const float* __restrict__ b2,
    const float* __restrict__ h_all, const float* __restrict__ cos_ws,
    const int* __restrict__ prefix, float* __restrict__ out) {
  __shared__ float hg_lds[HH * 64];    // [h][v]
  __shared__ float w2_lds[HH * 128];   // [h][kk]
  const int t = threadIdx.x;
  const int b = blockIdx.y;
  const size_t kbase = (size_t)blockIdx.x * 128;
  // stage w2 tile, float4 (1344 float4 over 256 threads)
  {
    const float4* w2g = (const float4*)w2;
    float4* w2l = (float4*)w2_lds;
    for (int i = t; i < HH * 32; i += 256) {
      int h = i >> 5, k4 = i & 31;
      w2l[i] = w2g[(size_t)h * (KK / 4) + (kbase >> 2) + k4];
    }
  }
  // per-thread redundant gate (no serial section, no barrier needed)
  float gate[PP];
  {
    float c[PP];
    float m = -1e30f;
    #pragma unroll
    for (int p = 0; p < PP; ++p) { c[p] = cos_ws[b * PP + p]; m = fmaxf(m, c[p]); }
    float s = 0.0f;
    #pragma unroll
    for (int p = 0; p < PP; ++p) { c[p] = expf(c[p] - m); s += c[p]; }
    float inv = 1.0f / s;
    float m2 = -1e30f;
    #pragma unroll
    for (int p = 0; p < PP; ++p) { c[p] *= inv; m2 = fmaxf(m2, c[p]); }
    float s2 = 0.0f;
    #pragma unroll
    for (int p = 0; p < PP; ++p) { c[p] = expf(c[p] - m2); s2 += c[p]; }
    float inv2 = 1.0f / s2;
    #pragma unroll
    for (int p = 0; p < PP; ++p) gate[p] = c[p] * inv2;
  }
  for (int idx = t; idx < 64 * HH; idx += 256) {
    int v = idx / HH;
    int h = idx - v * HH;
    int tokv = prefix[b * VV + v];
    float s = 0.0f;
    #pragma unroll
    for (int p = 0; p < PP; ++p)
      s += gate[p] * h_all[(size_t)(p * VV + tokv) * HH + h];
    hg_lds[h * 64 + v] = s;
  }
  __syncthreads();
  const int tk = t & 31, tb = t >> 5;
  float4 acc[8];
  #pragma unroll
  for (int i = 0; i < 8; ++i) acc[i] = make_float4(0.f, 0.f, 0.f, 0.f);
  const float4* w24 = (const float4*)w2_lds;
  const float4* hg4 = (const float4*)hg_lds;
  #pragma unroll 2
  for (int h = 0; h < HH; ++h) {
    float4 wv = w24[h * 32 + tk];
    float4 g0 = hg4[h * 16 + tb * 2];
    float4 g1 = hg4[h * 16 + tb * 2 + 1];
    float gg[8] = {g0.x, g0.y, g0.z, g0.w, g1.x, g1.y, g1.z, g1.w};
    #pragma unroll
    for (int i = 0; i < 8; ++i) {
      acc[i].x += gg[i] * wv.x;
      acc[i].y += gg[i] * wv.y;
      acc[i].z += gg[i] * wv.z;
      acc[i].w += gg[i] * wv.w;
    }
  }
  float4 b2v = ((const float4*)b2)[(kbase >> 2) + tk];
  float4* out4 = (float4*)out;
  #pragma unroll
  for (int i = 0; i < 8; ++i) {
    int bv = b * 64 + tb * 8 + i;
    float4 o;
    o.x = acc[i].x + b2v.x;
    o.y = acc[i].y + b2v.y;
    o.z = acc[i].z + b2v.z;
    o.w = acc[i].w + b2v.w;
    out4[(((size_t)bv * KK + kbase) >> 2) + tk] = o;
  }
}

extern "C" void kernel_launch(void* const* d_in, const int* in_sizes, int n_in,
                              void* d_out, int out_size, void* d_ws, size_t ws_size,
                              hipStream_t stream) {
  const int* prefix = (const int*)d_in[0];
  const float* ctx = (const float*)d_in[1];
  const float* tables = (const float*)d_in[2];
  const float* lora = (const float*)d_in[3];
  const float* w1 = (const float*)d_in[4];
  const float* b1 = (const float*)d_in[5];
  const float* w2 = (const float*)d_in[6];
  const float* b2 = (const float*)d_in[7];
  float* out = (float*)d_out;
  char* ws = (char*)d_ws;
  // workspace (bytes): part 8388608 | cos 128 | h_all 86016  (~8.5 MB)
  float* part = (float*)ws;
  float* cos_ws = (float*)(ws + 8388608);
  float* h_all = (float*)(ws + 8388608 + 128);

  kU<<<dim3(64, 4), 512, 0, stream>>>(ctx, lora, part);
  k4h<<<dim3(32 + 512), 512, 0, stream>>>(part, lora, tables, w1, b1,
                                          cos_ws, h_all);
  k7_out<<<dim3(384, 4), 256, 0, stream>>>(w2, b2, h_all, cos_ws, prefix, out);
}